// Round 1
// baseline (179.109 us; speedup 1.0000x reference)
//
#include <hip/hip_runtime.h>
#include <hip/hip_bf16.h>

#define LRELU_ALPHA 0.2f
#define MASKV -9.0e15f

constexpr int N   = 8192;
constexpr int FIN = 512;
constexpr int F   = 128;
constexpr int BR  = 32;      // rows per block in fused kernel
constexpr int BC  = 64;      // j-tile width
constexpr int NT  = N / BC;  // 128 tiles

typedef __attribute__((ext_vector_type(4))) float f32x4;
typedef __attribute__((ext_vector_type(8))) short s16x8;
typedef __attribute__((ext_vector_type(4))) short s16x4;
typedef __attribute__((ext_vector_type(4))) int   i32x4;

static __device__ __forceinline__ short f2bf(float x) {
  unsigned u = __float_as_uint(x);
  unsigned r = (u + 0x7fffu + ((u >> 16) & 1u)) >> 16;   // RNE bf16
  return (short)r;
}

// ---------------------------------------------------------------------------
// K1: Wh = h @ w (f32, [N][F]) and WhbT = Wh^T as bf16 ([F][N]) for MFMA B.
// 256 blocks x 256 threads, 32-row x 128-col tile, K chunks of 64 in LDS.
// ---------------------------------------------------------------------------
__global__ __launch_bounds__(256) void k_wh(
    const float* __restrict__ h, const float* __restrict__ w,
    float* __restrict__ Wh, __hip_bfloat16* __restrict__ WhbT) {
  __shared__ float hl[32][68];    // +4 pad keeps 16B align & spreads banks
  __shared__ float wl[64][128];
  const int t    = threadIdx.x;
  const int i0   = blockIdx.x * 32;
  const int col4 = (t & 31) * 4;  // 0..124
  const int rq   = t >> 5;        // 0..7 -> rows rq*4..rq*4+3
  float acc[4][4] = {};

  for (int k0 = 0; k0 < FIN; k0 += 64) {
#pragma unroll
    for (int j = 0; j < 2; ++j) {
      int c = t + 256 * j;
      int r = c >> 4, kq = c & 15;
      *(f32x4*)&hl[r][kq * 4] =
          *(const f32x4*)(h + (size_t)(i0 + r) * FIN + k0 + kq * 4);
    }
#pragma unroll
    for (int j = 0; j < 8; ++j) {
      int c = t + 256 * j;
      int kr = c >> 5, f4 = (c & 31) * 4;
      *(f32x4*)&wl[kr][f4] = *(const f32x4*)(w + (size_t)(k0 + kr) * F + f4);
    }
    __syncthreads();
#pragma unroll 4
    for (int k4 = 0; k4 < 64; k4 += 4) {
      f32x4 wv[4];
#pragma unroll
      for (int u = 0; u < 4; ++u) wv[u] = *(const f32x4*)&wl[k4 + u][col4];
#pragma unroll
      for (int ri = 0; ri < 4; ++ri) {
        f32x4 hv = *(const f32x4*)&hl[rq * 4 + ri][k4];
#pragma unroll
        for (int u = 0; u < 4; ++u) {
#pragma unroll
          for (int ci = 0; ci < 4; ++ci) acc[ri][ci] += hv[u] * wv[u][ci];
        }
      }
    }
    __syncthreads();
  }
#pragma unroll
  for (int ri = 0; ri < 4; ++ri) {
    int row = i0 + rq * 4 + ri;
    f32x4 o = {acc[ri][0], acc[ri][1], acc[ri][2], acc[ri][3]};
    *(f32x4*)(Wh + (size_t)row * F + col4) = o;
  }
#pragma unroll
  for (int ci = 0; ci < 4; ++ci) {
    int f = col4 + ci;
    s16x4 o = {f2bf(acc[0][ci]), f2bf(acc[1][ci]),
               f2bf(acc[2][ci]), f2bf(acc[3][ci])};
    *(s16x4*)((short*)WhbT + (size_t)f * N + i0 + rq * 4) = o;
  }
}

// ---------------------------------------------------------------------------
// K2: Wh1[i] = Wh[i,:]@a[0:128], Wh2[i] = Wh[i,:]@a[128:256]. One wave/row.
// ---------------------------------------------------------------------------
__global__ __launch_bounds__(64) void k_av(
    const float* __restrict__ Wh, const float* __restrict__ a,
    float* __restrict__ Wh1, float* __restrict__ Wh2) {
  int i = blockIdx.x, t = threadIdx.x;
  float v0 = Wh[(size_t)i * F + t];
  float v1 = Wh[(size_t)i * F + t + 64];
  float s1 = v0 * a[t] + v1 * a[t + 64];
  float s2 = v0 * a[F + t] + v1 * a[F + t + 64];
#pragma unroll
  for (int o = 1; o < 64; o <<= 1) {
    s1 += __shfl_xor(s1, o);
    s2 += __shfl_xor(s2, o);
  }
  if (t == 0) { Wh1[i] = s1; Wh2[i] = s2; }
}

// ---------------------------------------------------------------------------
// K3: fused flash-style GAT attention.
// grid 256, block 256 (4 waves). Each block: 32 rows, loops over 128 j-tiles
// of 64. Scores f32 -> online softmax -> P bf16 (LDS, XOR-swizzled, dbuf) ->
// MFMA 16x16x32 PV with B-fragments loaded directly from WhbT (global/L2).
// Single barrier per tile. adj prefetched 1 tile ahead (registers).
// ---------------------------------------------------------------------------
__global__ __launch_bounds__(256) void k_attn(
    const int* __restrict__ adj, const float* __restrict__ Wh1v,
    const float* __restrict__ Wh2v, const __hip_bfloat16* __restrict__ WhbT,
    float* __restrict__ out) {
  __shared__ __align__(16) short Pl[2][BR * BC];  // bf16 P, double-buffered
  __shared__ float alpha_l[2][BR];
  __shared__ float l_l[BR];

  const int t    = threadIdx.x;
  const int lane = t & 63;
  const int wv   = t >> 6;         // wave id: owns f columns [32w, 32w+32)
  const int c4   = (t & 15) * 4;   // j within tile (4 per thread)
  const int rb   = t >> 4;         // 0..15; rows rb and rb+16
  const int i0   = blockIdx.x * BR;

  const float w1_0 = Wh1v[i0 + rb];
  const float w1_1 = Wh1v[i0 + rb + 16];
  const size_t arow0 = (size_t)(i0 + rb) * N;
  const size_t arow1 = (size_t)(i0 + rb + 16) * N;

  float m0 = -INFINITY, m1 = -INFINITY, l0 = 0.f, l1 = 0.f;
  f32x4 acc[2][2] = {};

  i32x4 adjc0 = *(const i32x4*)(adj + arow0 + c4);
  i32x4 adjc1 = *(const i32x4*)(adj + arow1 + c4);
  f32x4 wh2c  = *(const f32x4*)(Wh2v + c4);
  i32x4 adjn0 = {}, adjn1 = {};
  f32x4 wh2n  = {};

  const short* bsrc = (const short*)WhbT;

  for (int tile = 0; tile < NT; ++tile) {
    const int j0 = tile * BC;
    if (tile + 1 < NT) {   // prefetch next adj/Wh2 tile into registers
      adjn0 = *(const i32x4*)(adj + arow0 + j0 + BC + c4);
      adjn1 = *(const i32x4*)(adj + arow1 + j0 + BC + c4);
      wh2n  = *(const f32x4*)(Wh2v + j0 + BC + c4);
    }
    // issue B-fragment loads now; consumed after the barrier
    s16x8 bf[2][2];
#pragma unroll
    for (int nb = 0; nb < 2; ++nb) {
#pragma unroll
      for (int kb = 0; kb < 2; ++kb) {
        int fc = wv * 32 + nb * 16 + (lane & 15);
        int kk = j0 + kb * 32 + (lane >> 4) * 8;
        bf[nb][kb] = *(const s16x8*)(bsrc + (size_t)fc * N + kk);
      }
    }
    // ---- scores + online softmax (row p=0: rb, p=1: rb+16) ----
    float pv0[4], pv1[4], al0, al1;
    {
      float sc[4]; float mx = MASKV;
#pragma unroll
      for (int u = 0; u < 4; ++u) {
        float x = w1_0 + wh2c[u];
        x = fmaxf(x, LRELU_ALPHA * x);              // LeakyReLU
        sc[u] = adjc0[u] > 0 ? x : MASKV;
        mx = fmaxf(mx, sc[u]);
      }
#pragma unroll
      for (int o = 1; o < 16; o <<= 1) mx = fmaxf(mx, __shfl_xor(mx, o));
      float mn = fmaxf(m0, mx);
      al0 = __expf(m0 - mn);
      float s = 0.f;
#pragma unroll
      for (int u = 0; u < 4; ++u) { pv0[u] = __expf(sc[u] - mn); s += pv0[u]; }
#pragma unroll
      for (int o = 1; o < 16; o <<= 1) s += __shfl_xor(s, o);
      l0 = l0 * al0 + s; m0 = mn;
    }
    {
      float sc[4]; float mx = MASKV;
#pragma unroll
      for (int u = 0; u < 4; ++u) {
        float x = w1_1 + wh2c[u];
        x = fmaxf(x, LRELU_ALPHA * x);
        sc[u] = adjc1[u] > 0 ? x : MASKV;
        mx = fmaxf(mx, sc[u]);
      }
#pragma unroll
      for (int o = 1; o < 16; o <<= 1) mx = fmaxf(mx, __shfl_xor(mx, o));
      float mn = fmaxf(m1, mx);
      al1 = __expf(m1 - mn);
      float s = 0.f;
#pragma unroll
      for (int u = 0; u < 4; ++u) { pv1[u] = __expf(sc[u] - mn); s += pv1[u]; }
#pragma unroll
      for (int o = 1; o < 16; o <<= 1) s += __shfl_xor(s, o);
      l1 = l1 * al1 + s; m1 = mn;
    }
    // ---- write P (bf16, swizzled) + alpha ----
    const int buf = tile & 1;
    char* pb = (char*)&Pl[buf][0];
    {
      int r = rb;
      s16x4 pk = {f2bf(pv0[0]), f2bf(pv0[1]), f2bf(pv0[2]), f2bf(pv0[3])};
      *(s16x4*)(pb + ((r * 128 + c4 * 2) ^ ((r & 7) << 4))) = pk;
    }
    {
      int r = rb + 16;
      s16x4 pk = {f2bf(pv1[0]), f2bf(pv1[1]), f2bf(pv1[2]), f2bf(pv1[3])};
      *(s16x4*)(pb + ((r * 128 + c4 * 2) ^ ((r & 7) << 4))) = pk;
    }
    if ((t & 15) == 0) { alpha_l[buf][rb] = al0; alpha_l[buf][rb + 16] = al1; }
    adjc0 = adjn0; adjc1 = adjn1; wh2c = wh2n;
    __syncthreads();
    // ---- rescale accumulators by alpha[row] ----
#pragma unroll
    for (int mb = 0; mb < 2; ++mb) {
      float av[4];
#pragma unroll
      for (int rg = 0; rg < 4; ++rg)
        av[rg] = alpha_l[buf][mb * 16 + (lane >> 4) * 4 + rg];
#pragma unroll
      for (int nb = 0; nb < 2; ++nb) {
#pragma unroll
        for (int rg = 0; rg < 4; ++rg) acc[mb][nb][rg] *= av[rg];
      }
    }
    // ---- A fragments from swizzled P ----
    s16x8 af[2][2];
#pragma unroll
    for (int mb = 0; mb < 2; ++mb) {
#pragma unroll
      for (int kb = 0; kb < 2; ++kb) {
        int row = mb * 16 + (lane & 15);
        int off = (row * 128 + kb * 64 + (lane >> 4) * 16) ^ ((row & 7) << 4);
        af[mb][kb] = *(const s16x8*)(pb + off);
      }
    }
    // ---- PV MFMA ----
#pragma unroll
    for (int mb = 0; mb < 2; ++mb) {
#pragma unroll
      for (int nb = 0; nb < 2; ++nb) {
#pragma unroll
        for (int kb = 0; kb < 2; ++kb)
          acc[mb][nb] = __builtin_amdgcn_mfma_f32_16x16x32_bf16(
              af[mb][kb], bf[nb][kb], acc[mb][nb], 0, 0, 0);
      }
    }
  }
  // ---- epilogue: normalize, ELU, store ----
  if ((t & 15) == 0) { l_l[rb] = l0; l_l[rb + 16] = l1; }
  __syncthreads();
#pragma unroll
  for (int mb = 0; mb < 2; ++mb) {
#pragma unroll
    for (int nb = 0; nb < 2; ++nb) {
#pragma unroll
      for (int rg = 0; rg < 4; ++rg) {
        int row = mb * 16 + (lane >> 4) * 4 + rg;
        int col = wv * 32 + nb * 16 + (lane & 15);
        float x = acc[mb][nb][rg] / l_l[row];
        x = x > 0.f ? x : __expf(x) - 1.f;           // ELU
        out[(size_t)(i0 + row) * F + col] = x;
      }
    }
  }
}

// ---------------------------------------------------------------------------
extern "C" void kernel_launch(void* const* d_in, const int* in_sizes, int n_in,
                              void* d_out, int out_size, void* d_ws, size_t ws_size,
                              hipStream_t stream) {
  const float* h   = (const float*)d_in[0];
  const int*   adj = (const int*)d_in[1];
  const float* w   = (const float*)d_in[2];
  const float* a   = (const float*)d_in[3];
  float* out = (float*)d_out;

  // workspace layout: Wh f32 (4MB) | WhbT bf16 (2MB) | Wh1 (32KB) | Wh2 (32KB)
  char* ws = (char*)d_ws;
  float* Wh = (float*)ws;
  __hip_bfloat16* WhbT = (__hip_bfloat16*)(ws + (size_t)N * F * 4);
  float* Wh1 = (float*)(ws + (size_t)N * F * 6);
  float* Wh2 = Wh1 + N;

  k_wh<<<N / 32, 256, 0, stream>>>(h, w, Wh, WhbT);
  k_av<<<N, 64, 0, stream>>>(Wh, a, Wh1, Wh2);
  k_attn<<<N / BR, 256, 0, stream>>>(adj, Wh1, Wh2, WhbT, out);
}